// Round 6
// baseline (367.438 us; speedup 1.0000x reference)
//
#include <hip/hip_runtime.h>

typedef unsigned int uu32;

#define NN 14      // nodes
#define FD 24      // SEQ / feature dim
#define HD 64      // GAT hidden
#define NE 70      // 56 edges + 14 self loops
#define BB 32768   // batch
#define SPW 4      // samples per wave(=block)
#define K1_BLOCKS (BB / SPW)           // 8192 single-wave blocks
#define K2_BLOCKS (NN * (BB / 256))    // 1792
#define HAP 68     // padded row stride for H1/A1 (16B-aligned rows)
#define H2P 28     // padded row stride for H2 (16B-aligned rows)

// GAT stage: G = conv2(elu(conv1(x))) -> Gout[14][B][24] f32 (Gout == d_out;
// the MLP kernel rewrites d_out in place afterwards — green since r4).
// Single-wave workgroup: __syncthreads() compiles to a waitcnt (no s_barrier
// needed for <=64 threads), so the 9 phase-fences per sample are near-free.
__global__ __launch_bounds__(64) void gat_k(
    const float* __restrict__ x, const int* __restrict__ ei,
    const float* __restrict__ W1, const float* __restrict__ as1,
    const float* __restrict__ ad1, const float* __restrict__ b1,
    const float* __restrict__ W2, const float* __restrict__ as2,
    const float* __restrict__ ad2, const float* __restrict__ b2,
    float* __restrict__ Gout) {
    __shared__ __align__(16) float HAw[NN * HAP];   // H1 then A1
    __shared__ __align__(16) float H2w[NN * H2P];
    __shared__ __align__(16) float Pw[256];         // unnormalized exp rows
    __shared__ float sdw[2 * NN];                   // src/dst dots
    __shared__ float smw[NN];                       // per-dst exp sums
    __shared__ __align__(16) float a1S[2 * HD];
    __shared__ __align__(16) float a2S[2 * FD];
    __shared__ int esS[NE], edS[NE];

    const int lane = threadIdx.x;

    a1S[lane] = as1[lane];
    a1S[HD + lane] = ad1[lane];
    if (lane < FD) { a2S[lane] = as2[lane]; a2S[FD + lane] = ad2[lane]; }
    // edge staging: robust to int64 (lo/hi dword pairs) or int32 delivery
    if (lane < 56) {
        int e64 = 1;
        for (int i = 0; i < 8; i++)
            if (ei[2 * i + 1] != 0 || (uu32)ei[2 * i] >= (uu32)NN) e64 = 0;
        esS[lane] = e64 ? ei[2 * lane] : ei[lane];
        edS[lane] = e64 ? ei[112 + 2 * lane] : ei[56 + lane];
    } else {
        esS[lane] = edS[lane] = lane - 56;     // self loops, nodes 0..7
    }
    if (lane < NE - 64) esS[64 + lane] = edS[64 + lane] = 8 + lane;  // 8..13

    // per-lane resident weights
    float w1r[FD];
#pragma unroll
    for (int f = 0; f < FD; f++) w1r[f] = W1[f * HD + lane];
    const float b1r = b1[lane];
    const int f2 = lane % FD;
    const int g2 = lane / FD;      // 0,1 active for 24-wide stages
    float w2r[HD];
#pragma unroll
    for (int k = 0; k < HD; k++) w2r[k] = W2[k * FD + f2];
    const float b2r = b2[f2];
    __syncthreads();
    // edge ownership: edge0 = lane (0..63); lanes 0..5 also own 64..69
    const bool ex = (lane < NE - 64);
    const int s0 = esS[lane], d0 = edS[lane];
    const int s1 = esS[ex ? 64 + lane : 0], d1 = edS[ex ? 64 + lane : 0];

    for (int t = 0; t < SPW; t++) {
        const size_t b = (size_t)blockIdx.x * SPW + t;   // wave-uniform
        // ---- 2. H1 = X @ W1 : X read via uniform scalar loads (s_load);
        //         lane owns hidden col `lane`; rows in regs ----
        const float* __restrict__ xb = x + b * (NN * FD);   // uniform base
        float acc[NN];
#pragma unroll
        for (int n = 0; n < NN; n++) acc[n] = 0.0f;
#pragma unroll
        for (int f = 0; f < FD; f++) {
            const float wf = w1r[f];
#pragma unroll
            for (int n = 0; n < NN; n++)
                acc[n] = fmaf(xb[f * NN + n], wf, acc[n]);   // s_load * vgpr
        }
#pragma unroll
        for (int n = 0; n < NN; n++) HAw[n * HAP + lane] = acc[n];
        __syncthreads();
        // ---- 3. src/dst dots (28 lanes) + zero P/sums ----
        if (lane < 2 * NN) {
            const int v = (lane >= NN) ? 1 : 0;
            const int n2 = lane - v * NN;
            float s = 0.0f;
#pragma unroll
            for (int k = 0; k < 16; k++) {
                float4 h4 = *(const float4*)&HAw[n2 * HAP + 4 * k];
                float4 a4 = *(const float4*)&a1S[v * HD + 4 * k];
                s = fmaf(h4.x, a4.x, s); s = fmaf(h4.y, a4.y, s);
                s = fmaf(h4.z, a4.z, s); s = fmaf(h4.w, a4.w, s);
            }
            sdw[v * NN + n2] = s;
        }
        *(float4*)&Pw[lane * 4] = make_float4(0.f, 0.f, 0.f, 0.f);
        if (lane < NN) smw[lane] = 0.0f;
        __syncthreads();
        // ---- 4. softmax1 (shift-invariant, no max pass: |alpha| << 88) ----
        {
            float a = sdw[s0] + sdw[NN + d0];
            a = a > 0.0f ? a : 0.2f * a;               // leaky_relu(0.2)
            float e0 = __expf(a);
            atomicAdd(&smw[d0], e0);
            atomicAdd(&Pw[d0 * 16 + s0], e0);          // unnormalized
            if (ex) {
                a = sdw[s1] + sdw[NN + d1];
                a = a > 0.0f ? a : 0.2f * a;
                float e1 = __expf(a);
                atomicAdd(&smw[d1], e1);
                atomicAdd(&Pw[d1 * 16 + s1], e1);
            }
        }
        __syncthreads();
        // ---- 5. A1 = ELU(P @ H1 / sum + b1); H1 from regs ----
        float acc2[NN];
#pragma unroll
        for (int n = 0; n < NN; n++) {
            float a = 0.0f;
#pragma unroll
            for (int k4 = 0; k4 < 3; k4++) {
                float4 p4 = *(const float4*)&Pw[n * 16 + 4 * k4];   // broadcast
                a = fmaf(p4.x, acc[4 * k4 + 0], a);
                a = fmaf(p4.y, acc[4 * k4 + 1], a);
                a = fmaf(p4.z, acc[4 * k4 + 2], a);
                a = fmaf(p4.w, acc[4 * k4 + 3], a);
            }
            float4 p4 = *(const float4*)&Pw[n * 16 + 12];
            a = fmaf(p4.x, acc[12], a);
            a = fmaf(p4.y, acc[13], a);
            a = __fdividef(a, smw[n]) + b1r;
            acc2[n] = a > 0.0f ? a : (__expf(a) - 1.0f);   // ELU
        }
#pragma unroll
        for (int n = 0; n < NN; n++) HAw[n * HAP + lane] = acc2[n];
        __syncthreads();
        // ---- 6. H2 = A1 @ W2 : lane (g2,f2) covers 7 nodes ----
        if (g2 < 2) {
#pragma unroll
            for (int i = 0; i < 7; i++) {
                const int n = g2 + 2 * i;
                float a = 0.0f;
#pragma unroll
                for (int k4 = 0; k4 < 16; k4++) {
                    float4 v4 = *(const float4*)&HAw[n * HAP + 4 * k4];
                    a = fmaf(v4.x, w2r[4 * k4 + 0], a);
                    a = fmaf(v4.y, w2r[4 * k4 + 1], a);
                    a = fmaf(v4.z, w2r[4 * k4 + 2], a);
                    a = fmaf(v4.w, w2r[4 * k4 + 3], a);
                }
                H2w[n * H2P + f2] = a;
            }
        }
        __syncthreads();
        // ---- 7. conv2 dots (28 lanes) + zero P/sums ----
        if (lane < 2 * NN) {
            const int v = (lane >= NN) ? 1 : 0;
            const int n2 = lane - v * NN;
            float s = 0.0f;
#pragma unroll
            for (int q = 0; q < 6; q++) {
                float4 h4 = *(const float4*)&H2w[n2 * H2P + 4 * q];
                float4 a4 = *(const float4*)&a2S[v * FD + 4 * q];
                s = fmaf(h4.x, a4.x, s); s = fmaf(h4.y, a4.y, s);
                s = fmaf(h4.z, a4.z, s); s = fmaf(h4.w, a4.w, s);
            }
            sdw[v * NN + n2] = s;
        }
        *(float4*)&Pw[lane * 4] = make_float4(0.f, 0.f, 0.f, 0.f);
        if (lane < NN) smw[lane] = 0.0f;
        __syncthreads();
        // ---- 8. softmax2 ----
        {
            float a = sdw[s0] + sdw[NN + d0];
            a = a > 0.0f ? a : 0.2f * a;
            float e0 = __expf(a);
            atomicAdd(&smw[d0], e0);
            atomicAdd(&Pw[d0 * 16 + s0], e0);
            if (ex) {
                a = sdw[s1] + sdw[NN + d1];
                a = a > 0.0f ? a : 0.2f * a;
                float e1 = __expf(a);
                atomicAdd(&smw[d1], e1);
                atomicAdd(&Pw[d1 * 16 + s1], e1);
            }
        }
        __syncthreads();
        // ---- 9. G = P2 @ H2 / sum + b2 -> d_out [14][B][24] ----
        if (g2 < 2) {
            float h2c[NN];
#pragma unroll
            for (int k = 0; k < NN; k++) h2c[k] = H2w[k * H2P + f2];
#pragma unroll
            for (int i = 0; i < 7; i++) {
                const int n = g2 + 2 * i;
                float a = 0.0f;
#pragma unroll
                for (int k4 = 0; k4 < 3; k4++) {
                    float4 p4 = *(const float4*)&Pw[n * 16 + 4 * k4];
                    a = fmaf(p4.x, h2c[4 * k4 + 0], a);
                    a = fmaf(p4.y, h2c[4 * k4 + 1], a);
                    a = fmaf(p4.z, h2c[4 * k4 + 2], a);
                    a = fmaf(p4.w, h2c[4 * k4 + 3], a);
                }
                float4 p4 = *(const float4*)&Pw[n * 16 + 12];
                a = fmaf(p4.x, h2c[12], a);
                a = fmaf(p4.y, h2c[13], a);
                Gout[((size_t)n * BB + b) * FD + f2] =
                    __fdividef(a, smw[n]) + b2r;
            }
        }
        __syncthreads();   // protect reused LDS before next sample
    }
}

// MLP stage, in place on d_out. One thread per (node, sample) row. All
// weight/bias accesses are wave-uniform (n from blockIdx, indices affine in
// unrolled loop constants) -> scalar s_load path: no LDS, no VMEM replication.
__global__ __launch_bounds__(256) void mlp_k(
    const float* __restrict__ fc1w, const float* __restrict__ fc1b,
    const float* __restrict__ fc2w, const float* __restrict__ fc2b,
    float* gio) {
    const int t = threadIdx.x;
    const int n = blockIdx.x >> 7;             // 128 blocks per node
    const int b0 = (blockIdx.x & 127) * 256;

    const float* __restrict__ w1 = fc1w + (size_t)n * (FD * HD);  // [f][j]
    const float* __restrict__ w2 = fc2w + (size_t)n * (HD * FD);  // [j][f]
    const float* __restrict__ bias1 = fc1b + n * HD;
    const float* __restrict__ bias2 = fc2b + n * FD;

    const size_t base = ((size_t)n * BB + b0 + t) * FD;
    float g[FD], o[FD];
#pragma unroll
    for (int q = 0; q < 6; q++)
        *(float4*)&g[4 * q] = *(const float4*)&gio[base + 4 * q];
#pragma unroll
    for (int f = 0; f < FD; f++) o[f] = bias2[f];

#pragma unroll 2
    for (int j4 = 0; j4 < 16; j4++) {
        float h0 = bias1[4 * j4 + 0], h1 = bias1[4 * j4 + 1];
        float h2 = bias1[4 * j4 + 2], h3 = bias1[4 * j4 + 3];
#pragma unroll
        for (int f = 0; f < FD; f++) {
            h0 = fmaf(g[f], w1[f * HD + 4 * j4 + 0], h0);   // s_load x4
            h1 = fmaf(g[f], w1[f * HD + 4 * j4 + 1], h1);
            h2 = fmaf(g[f], w1[f * HD + 4 * j4 + 2], h2);
            h3 = fmaf(g[f], w1[f * HD + 4 * j4 + 3], h3);
        }
        h0 = fmaxf(h0, 0.f); h1 = fmaxf(h1, 0.f);
        h2 = fmaxf(h2, 0.f); h3 = fmaxf(h3, 0.f);
        float hv[4] = {h0, h1, h2, h3};
#pragma unroll
        for (int u2 = 0; u2 < 4; u2++) {
            const int j = 4 * j4 + u2;
#pragma unroll
            for (int f = 0; f < FD; f++)
                o[f] = fmaf(hv[u2], w2[j * FD + f], o[f]);  // s_load
        }
    }
#pragma unroll
    for (int q = 0; q < 6; q++)
        *(float4*)&gio[base + 4 * q] = *(const float4*)&o[4 * q];
}

extern "C" void kernel_launch(void* const* d_in, const int* in_sizes, int n_in,
                              void* d_out, int out_size, void* d_ws, size_t ws_size,
                              hipStream_t stream) {
    (void)in_sizes; (void)n_in; (void)out_size; (void)d_ws; (void)ws_size;
    const float* x    = (const float*)d_in[0];
    const int*   ei   = (const int*)d_in[1];
    const float* W1   = (const float*)d_in[2];
    const float* as1  = (const float*)d_in[3];
    const float* ad1  = (const float*)d_in[4];
    const float* b1   = (const float*)d_in[5];
    const float* W2   = (const float*)d_in[6];
    const float* as2  = (const float*)d_in[7];
    const float* ad2  = (const float*)d_in[8];
    const float* b2   = (const float*)d_in[9];
    const float* fc1w = (const float*)d_in[10];
    const float* fc1b = (const float*)d_in[11];
    const float* fc2w = (const float*)d_in[12];
    const float* fc2b = (const float*)d_in[13];
    float* gio = (float*)d_out;   // G staged in d_out, MLP rewrites in place

    gat_k<<<dim3(K1_BLOCKS), dim3(64), 0, stream>>>(
        x, ei, W1, as1, ad1, b1, W2, as2, ad2, b2, gio);
    mlp_k<<<dim3(K2_BLOCKS), dim3(256), 0, stream>>>(
        fc1w, fc1b, fc2w, fc2b, gio);
}